// Round 22
// baseline (161.981 us; speedup 1.0000x reference)
//
#include <hip/hip_runtime.h>
#include <hip/hip_fp16.h>

#define IN_CH 128
#define HC 256      // HEADS*OUT_CH
#define OUT_CH 64
#define NEG 0.2f
#define BN_EPS 1e-5f
#define APITCH 136   // bf16 LDS pitch
#define CSR_CAP 4096 // per-bucket capacity (128 dst nodes/bucket, avg ~2.2K edges)

typedef __attribute__((ext_vector_type(8))) short short8v;
typedef __attribute__((ext_vector_type(4))) float f32x4v;

// ---------- helpers ----------
__device__ __forceinline__ float4 add4(float4 a, float4 b) {
    return make_float4(a.x + b.x, a.y + b.y, a.z + b.z, a.w + b.w);
}
__device__ __forceinline__ float4 mul4(float4 a, float4 b) {
    return make_float4(a.x * b.x, a.y * b.y, a.z * b.z, a.w * b.w);
}
__device__ __forceinline__ float4 exp4f(float4 a) {
    return make_float4(__expf(a.x), __expf(a.y), __expf(a.z), __expf(a.w));
}
__device__ __forceinline__ float4 leaky4(float4 v) {
    v.x = v.x > 0.f ? v.x : v.x * NEG;
    v.y = v.y > 0.f ? v.y : v.y * NEG;
    v.z = v.z > 0.f ? v.z : v.z * NEG;
    v.w = v.w > 0.f ? v.w : v.w * NEG;
    return v;
}
__device__ __forceinline__ unsigned short f2bf(float f) {
    unsigned u = __float_as_uint(f);
    unsigned r = u + 0x7fffu + ((u >> 16) & 1u);   // round-to-nearest-even
    return (unsigned short)(r >> 16);
}
// pack two f32 -> two fp16 in one dword; unpack
__device__ __forceinline__ unsigned pkh2(float a, float b) {
    return (unsigned)__half_as_ushort(__float2half_rn(a)) |
           ((unsigned)__half_as_ushort(__float2half_rn(b)) << 16);
}
__device__ __forceinline__ float h2lo(unsigned u) {
    return __half2float(__ushort_as_half((unsigned short)(u & 0xffffu)));
}
__device__ __forceinline__ float h2hi(unsigned u) {
    return __half2float(__ushort_as_half((unsigned short)(u >> 16)));
}
// int8 dequant-accumulate: 4 biased bytes of u scaled by ws into acc
__device__ __forceinline__ void acc8(float4& a, float ws, unsigned u) {
    a.x += ws * (float)(u & 0xffu);
    a.y += ws * (float)((u >> 8) & 0xffu);
    a.z += ws * (float)((u >> 16) & 0xffu);
    a.w += ws * (float)(u >> 24);
}

// ---- K0: wt in MFMA-FRAGMENT order + zero bucket_cnt/sums/sqs (640 words) ----
__global__ __launch_bounds__(256) void prep_wt(const float* __restrict__ W,
                                               unsigned short* __restrict__ wt,
                                               unsigned* __restrict__ zeros, int nz) {
    int idx = blockIdx.x * 256 + threadIdx.x;
    if (idx < nz) zeros[idx] = 0u;
    if (idx >= 64 * 64) return;
    int frag = idx >> 6, l = idx & 63;
    int j = frag >> 2, ks = frag & 3;
    int c = l & 15, g = l >> 4;
    int ch = c * 16 + j;
    int k0 = ks * 32 + g * 8;
    unsigned up[4];
    #pragma unroll
    for (int q = 0; q < 4; ++q) {
        unsigned short lo = f2bf(W[(size_t)(k0 + 2 * q) * HC + ch]);
        unsigned short hi = f2bf(W[(size_t)(k0 + 2 * q + 1) * HC + ch]);
        up[q] = (unsigned)lo | ((unsigned)hi << 16);
    }
    *(uint4*)(wt + (size_t)idx * 8) = make_uint4(up[0], up[1], up[2], up[3]);
}

// ---- K1 (fat): blocks [0, gemmBlocks) = MFMA GEMM; rest = bucket_scatter ----
__global__ __launch_bounds__(256) void gemm_and_scatter(const float* __restrict__ x,
                                                        const unsigned short* __restrict__ wt,
                                                        const float* __restrict__ att_src,
                                                        const float* __restrict__ att_dst,
                                                        unsigned char* __restrict__ xq,
                                                        float* __restrict__ pks,
                                                        float* __restrict__ adst, int N,
                                                        const int* __restrict__ ei,
                                                        unsigned* __restrict__ bucket_cnt,
                                                        unsigned* __restrict__ bucketbuf,
                                                        int E, int gemmBlocks) {
    __shared__ unsigned short Al[64][APITCH];              // gemm path
    __shared__ unsigned lcnt[512], lbase[512], lcur[512];  // scatter path
    int t = threadIdx.x;

    if ((int)blockIdx.x >= gemmBlocks) {
        // ---------------- bucket_scatter ----------------
        lcnt[t] = 0u; lcnt[t + 256] = 0u;
        lcur[t] = 0u; lcur[t + 256] = 0u;
        __syncthreads();
        int c0 = ((int)blockIdx.x - gemmBlocks) * 4096;
        unsigned rec[16];
        int bk[16];
        #pragma unroll
        for (int i = 0; i < 16; ++i) {
            int e = c0 + t + i * 256;
            bk[i] = -1;
            if (e < E) {
                unsigned s = (unsigned)ei[e];
                unsigned d = (unsigned)ei[E + e];
                rec[i] = s | ((d & 127u) << 16);
                bk[i] = (int)(d >> 7);
                atomicAdd(&lcnt[bk[i]], 1u);
            }
        }
        __syncthreads();
        #pragma unroll
        for (int h = 0; h < 2; ++h) {
            int bi = t + h * 256;
            lbase[bi] = lcnt[bi] ? atomicAdd(&bucket_cnt[bi], lcnt[bi]) : 0u;
        }
        __syncthreads();
        #pragma unroll
        for (int i = 0; i < 16; ++i) {
            if (bk[i] >= 0) {
                unsigned p = lbase[bk[i]] + atomicAdd(&lcur[bk[i]], 1u);
                if (p < CSR_CAP) bucketbuf[(size_t)bk[i] * CSR_CAP + p] = rec[i];
            }
        }
        return;
    }

    // ---------------- gemm_mfma (LDS-staged A) ----------------
    int r0 = blockIdx.x * 64;
    #pragma unroll
    for (int i = 0; i < 8; ++i) {
        int f4 = t + i * 256;
        int m = f4 >> 5, kf = f4 & 31;
        float4 v = make_float4(0.f, 0.f, 0.f, 0.f);
        int r = r0 + m;
        if (r < N) v = *(const float4*)(x + (size_t)r * IN_CH + kf * 4);
        ushort4 pk;
        pk.x = f2bf(v.x); pk.y = f2bf(v.y); pk.z = f2bf(v.z); pk.w = f2bf(v.w);
        *(ushort4*)(&Al[m][kf * 4]) = pk;
    }
    __syncthreads();

    int w = t >> 6, l = t & 63;
    int c = l & 15, g = l >> 4;
    int arow = w * 16 + c;

    f32x4v acc[16];
    #pragma unroll
    for (int j = 0; j < 16; ++j) acc[j] = (f32x4v){0.f, 0.f, 0.f, 0.f};

    #pragma unroll
    for (int ks = 0; ks < 4; ++ks) {
        short8v a = *(const short8v*)(&Al[arow][ks * 32 + g * 8]);
        #pragma unroll
        for (int j = 0; j < 16; ++j) {
            short8v b = *(const short8v*)(wt + (size_t)((j * 4 + ks) * 64 + l) * 8);
            acc[j] = __builtin_amdgcn_mfma_f32_16x16x32_bf16(a, b, acc[j], 0, 0, 0);
        }
    }

    float as_c[16], ad_c[16];
    #pragma unroll
    for (int q = 0; q < 4; ++q) {
        *(float4*)(&as_c[q * 4]) = *(const float4*)(att_src + c * 16 + q * 4);
        *(float4*)(&ad_c[q * 4]) = *(const float4*)(att_dst + c * 16 + q * 4);
    }
    #pragma unroll
    for (int i = 0; i < 4; ++i) {
        int r = r0 + w * 16 + g * 4 + i;
        float ps = 0.f, pd = 0.f;
        float amax = 0.f;
        #pragma unroll
        for (int j = 0; j < 16; ++j) {
            float av = acc[j][i];
            ps += av * as_c[j];
            pd += av * ad_c[j];
            amax = fmaxf(amax, fabsf(av));
        }
        ps += __shfl_xor(ps, 1, 64); pd += __shfl_xor(pd, 1, 64);
        ps += __shfl_xor(ps, 2, 64); pd += __shfl_xor(pd, 2, 64);
        amax = fmaxf(amax, __shfl_xor(amax, 1, 64));
        amax = fmaxf(amax, __shfl_xor(amax, 2, 64));
        float inv = amax > 0.f ? 127.f / amax : 0.f;
        if (r < N) {
            int q4 = c & 3, h = c >> 2;
            if (q4 == 0) pks[(size_t)r * 8 + h] = ps;
            else if (q4 == 1) adst[(size_t)r * 4 + h] = pd;
            else if (q4 == 2) pks[(size_t)r * 8 + 4 + h] = amax * (1.f / 127.f);
            unsigned* orow = (unsigned*)(xq + (size_t)r * HC);
            #pragma unroll
            for (int q = 0; q < 4; ++q) {
                unsigned b0 = (unsigned)(int)fmaf(acc[q * 4 + 0][i], inv, 128.5f);
                unsigned b1 = (unsigned)(int)fmaf(acc[q * 4 + 1][i], inv, 128.5f);
                unsigned b2 = (unsigned)(int)fmaf(acc[q * 4 + 2][i], inv, 128.5f);
                unsigned b3 = (unsigned)(int)fmaf(acc[q * 4 + 3][i], inv, 128.5f);
                unsigned pk = b0 | (b1 << 8) | (b2 << 16) | (b3 << 24);
                orow[(((c & 3) * 4 + q) << 2) + h] = pk;
            }
        }
    }
}

// ---- CSR pass B + WEIGHT PRECOMPUTE: one 512-thread block per 128-dst bucket.
// Builds rowptr/ssrc AND the final per-edge softmax weights (f32x4), the
// per-node self weights and the per-node wssum (for the +128-bias removal).
__global__ __launch_bounds__(512) void bucket_csr(const unsigned* __restrict__ bucketbuf,
                                                  const unsigned* __restrict__ bucket_cnt,
                                                  const float* __restrict__ pks,
                                                  const float* __restrict__ adst,
                                                  unsigned* __restrict__ rowptr,
                                                  unsigned short* __restrict__ ssrc,
                                                  float* __restrict__ wsbuf,
                                                  float* __restrict__ selfws,
                                                  float* __restrict__ wssumbuf,
                                                  int N, int E, int NB) {
    __shared__ unsigned csum[512];
    __shared__ unsigned dcnt[128], dscan[128], curo[128];
    __shared__ unsigned sstage[CSR_CAP];   // src | dlo<<16, CSR order
    __shared__ uint2 exws[CSR_CAP];        // per-edge exp*scale, 4x fp16
    __shared__ float4 dadst[128], dsaw[128], dscw[128], dden[128];
    __shared__ float dwssum[128];
    int b = blockIdx.x, t = threadIdx.x;
    csum[t] = (t < NB) ? bucket_cnt[t] : 0u;
    if (t < 128) {
        dcnt[t] = 0u;
        int node = b * 128 + t;
        if (node < N) {
            dadst[t] = *(const float4*)(adst + (size_t)node * 4);
            dsaw[t]  = *(const float4*)(pks + (size_t)node * 8);
            dscw[t]  = *(const float4*)(pks + (size_t)node * 8 + 4);
        } else {
            dadst[t] = make_float4(0.f, 0.f, 0.f, 0.f);
            dsaw[t] = dadst[t]; dscw[t] = dadst[t];
        }
        dden[t] = make_float4(0.f, 0.f, 0.f, 0.f);
    }
    __syncthreads();
    for (int o = 1; o < 512; o <<= 1) {
        unsigned v = (t >= o) ? csum[t - o] : 0u;
        __syncthreads();
        csum[t] += v;
        __syncthreads();
    }
    unsigned base = (b == 0) ? 0u : csum[b - 1];
    unsigned nloc = bucket_cnt[b];
    if (nloc > CSR_CAP) nloc = CSR_CAP;
    const unsigned* bb = bucketbuf + (size_t)b * CSR_CAP;
    for (unsigned i = t; i < nloc; i += 512) atomicAdd(&dcnt[bb[i] >> 16], 1u);
    __syncthreads();
    if (t < 128) dscan[t] = dcnt[t];
    __syncthreads();
    for (int o = 1; o < 128; o <<= 1) {
        unsigned v = 0u;
        if (t < 128 && t >= o) v = dscan[t - o];
        __syncthreads();
        if (t < 128) dscan[t] += v;
        __syncthreads();
    }
    if (t < 128) {
        unsigned loff = dscan[t] - dcnt[t];
        curo[t] = loff;
        int node = b * 128 + t;
        if (node < N) rowptr[node] = base + loff;
    }
    if (b == 0 && t == 0) rowptr[N] = (unsigned)E;
    __syncthreads();
    for (unsigned i = t; i < nloc; i += 512) {
        unsigned r = bb[i];
        unsigned p = atomicAdd(&curo[r >> 16], 1u);
        sstage[p] = r;
    }
    __syncthreads();
    // pass 1: per-edge exp, accumulate per-dst denominator
    for (unsigned i = t; i < nloc; i += 512) {
        unsigned r = sstage[i];
        int s = (int)(r & 0xffffu), d = (int)(r >> 16);
        float4 as4 = *(const float4*)(pks + (size_t)s * 8);
        float4 sc4 = *(const float4*)(pks + (size_t)s * 8 + 4);
        float4 ex = exp4f(leaky4(add4(as4, dadst[d])));
        exws[i] = make_uint2(pkh2(ex.x * sc4.x, ex.y * sc4.y),
                             pkh2(ex.z * sc4.z, ex.w * sc4.w));
        float* dd = (float*)&dden[d];
        atomicAdd(dd + 0, ex.x); atomicAdd(dd + 1, ex.y);
        atomicAdd(dd + 2, ex.z); atomicAdd(dd + 3, ex.w);
    }
    __syncthreads();
    // self weight, per-dst inverse denominator
    if (t < 128) {
        int node = b * 128 + t;
        float4 selfex = exp4f(leaky4(add4(dsaw[t], dadst[t])));
        float4 den = add4(dden[t], selfex);
        float4 inv = make_float4(0.25f / den.x, 0.25f / den.y, 0.25f / den.z, 0.25f / den.w);
        dden[t] = inv;   // reuse as inv
        float4 sws = mul4(mul4(selfex, dscw[t]), inv);
        if (node < N) *(float4*)(selfws + (size_t)node * 4) = sws;
        dwssum[t] = sws.x + sws.y + sws.z + sws.w;
    }
    __syncthreads();
    // pass 2: finalize per-edge weights + write ssrc (coalesced)
    for (unsigned i = t; i < nloc; i += 512) {
        unsigned r = sstage[i];
        int s = (int)(r & 0xffffu), d = (int)(r >> 16);
        uint2 e2 = exws[i];
        float4 exs = make_float4(h2lo(e2.x), h2hi(e2.x), h2lo(e2.y), h2hi(e2.y));
        float4 ws = mul4(exs, dden[d]);
        *(float4*)(wsbuf + (size_t)(base + i) * 4) = ws;
        atomicAdd(&dwssum[d], ws.x + ws.y + ws.z + ws.w);
        ssrc[base + i] = (unsigned short)s;
    }
    __syncthreads();
    if (t < 128) {
        int node = b * 128 + t;
        if (node < N) wssumbuf[node] = dwssum[t];
    }
}

// ---- K_fused: pure int8 gather-accumulate; half-wave (32 lanes) per node.
// Weights precomputed by bucket_csr -> no shuffles, no exp, any degree.
__global__ __launch_bounds__(256) void node_fused(const unsigned short* __restrict__ ssrc,
                                                  const unsigned* __restrict__ rowptr,
                                                  const float* __restrict__ wsbuf,
                                                  const float* __restrict__ selfws,
                                                  const float* __restrict__ wssumbuf,
                                                  const unsigned char* __restrict__ xq,
                                                  float* __restrict__ out, int N) {
    int wid = (blockIdx.x * 256 + threadIdx.x) >> 5;
    if (wid >= N) return;
    int hlane = threadIdx.x & 31;
    int row0 = rowptr[wid];
    int deg = (int)rowptr[wid + 1] - row0;
    int grp = hlane >> 4, sub = hlane & 15;

    float4 acc = make_float4(0.f, 0.f, 0.f, 0.f);
    int nIter = (deg + 2) >> 1;              // ceil((deg+1)/2): edges + self
    #pragma unroll 4
    for (int it = 0; it < nIter; ++it) {
        int e = it * 2 + grp;
        int s;
        float4 ws4;
        if (e < deg) {
            s = ssrc[row0 + e];
            ws4 = *(const float4*)(wsbuf + (size_t)(row0 + e) * 4);
        } else if (e == deg) {
            s = wid;
            ws4 = *(const float4*)(selfws + (size_t)wid * 4);
        } else {
            s = wid;
            ws4 = make_float4(0.f, 0.f, 0.f, 0.f);
        }
        uint4 u = *(const uint4*)(xq + (size_t)s * HC + sub * 16);
        acc8(acc, ws4.x, u.x); acc8(acc, ws4.y, u.y);
        acc8(acc, ws4.z, u.z); acc8(acc, ws4.w, u.w);
    }

    // combine the 2 edge-groups (xor 16, width 32)
    acc.x += __shfl_xor(acc.x, 16, 32);
    acc.y += __shfl_xor(acc.y, 16, 32);
    acc.z += __shfl_xor(acc.z, 16, 32);
    acc.w += __shfl_xor(acc.w, 16, 32);
    float off = 128.f * wssumbuf[wid];
    if (hlane < 16) {
        float4 o4 = make_float4(acc.x - off, acc.y - off, acc.z - off, acc.w - off);
        *(float4*)(out + (size_t)wid * OUT_CH + sub * 4) = o4;
    }
}

// ---- K5: BN batch stats (bias cancels through BN -> omitted) ----
__global__ __launch_bounds__(256) void bn_stats(const float* __restrict__ out,
                                                float* __restrict__ sums,
                                                float* __restrict__ sqs, int N) {
    int c = threadIdx.x & 63, rl = threadIdx.x >> 6;
    float s = 0.f, q = 0.f;
    for (int r = blockIdx.x * 4 + rl; r < N; r += gridDim.x * 4) {
        float v = out[(size_t)r * 64 + c];
        s += v; q += v * v;
    }
    __shared__ float sb[256], qb[256];
    sb[threadIdx.x] = s; qb[threadIdx.x] = q;
    __syncthreads();
    if (rl == 0) {
        s = sb[c] + sb[64 + c] + sb[128 + c] + sb[192 + c];
        q = qb[c] + qb[64 + c] + qb[128 + c] + qb[192 + c];
        atomicAdd(sums + c, s);
        atomicAdd(sqs + c, q);
    }
}

// ---- K6: batchnorm + ELU, in place ----
__global__ __launch_bounds__(256) void finalize(float* __restrict__ out,
                                                const float* __restrict__ bnw,
                                                const float* __restrict__ bnb,
                                                const float* __restrict__ sums,
                                                const float* __restrict__ sqs, int N) {
    int idx = blockIdx.x * 256 + threadIdx.x;
    if (idx >= N * 64) return;
    int c = idx & 63;
    float invN = 1.0f / (float)N;
    float mu = sums[c] * invN;
    float var = sqs[c] * invN - mu * mu;
    float v = out[idx];
    float y = (v - mu) * rsqrtf(var + BN_EPS) * bnw[c] + bnb[c];
    out[idx] = y > 0.f ? y : expm1f(y);
}

extern "C" void kernel_launch(void* const* d_in, const int* in_sizes, int n_in,
                              void* d_out, int out_size, void* d_ws, size_t ws_size,
                              hipStream_t stream) {
    const float* x       = (const float*)d_in[0];
    const int*   ei      = (const int*)d_in[1];
    const float* W       = (const float*)d_in[2];
    const float* att_src = (const float*)d_in[3];
    const float* att_dst = (const float*)d_in[4];
    const float* bnw     = (const float*)d_in[6];
    const float* bnb     = (const float*)d_in[7];
    int N = in_sizes[0] / IN_CH;   // NOTE: src indices packed in uint16 (N < 65536)
    int E = in_sizes[1] / 2;
    float* out = (float*)d_out;
    int NB = (N + 127) / 128;      // 128 dsts per bucket

    // workspace layout (bucket_cnt, sums, sqs contiguous -> zeroed in prep_wt)
    unsigned char*  xq        = (unsigned char*)d_ws;                    // N*256 int8
    unsigned short* wt        = (unsigned short*)(xq + (size_t)N * HC);  // 64*64*8 bf16
    float*          pks       = (float*)(wt + 64 * 64 * 8);              // N*8 {asrc,scale}
    float*          adst      = pks + (size_t)N * 8;                     // N*4
    unsigned*       bucket_cnt= (unsigned*)(adst + (size_t)N * 4);       // 512
    float*          sums      = (float*)(bucket_cnt + 512);              // 64
    float*          sqs       = sums + 64;                               // 64
    unsigned*       rowptr    = (unsigned*)(sqs + 64);                   // N+1
    unsigned*       bucketbuf = rowptr + N + 1;                          // NB*CSR_CAP
    float*          wsbuf     = (float*)(bucketbuf + (size_t)NB * CSR_CAP); // E*4
    float*          selfws    = wsbuf + (size_t)E * 4;                   // N*4
    float*          wssumbuf  = selfws + (size_t)N * 4;                  // N
    unsigned short* ssrc      = (unsigned short*)(wssumbuf + N);         // E

    prep_wt<<<16, 256, 0, stream>>>(W, wt, bucket_cnt, 640);

    int gemmBlocks = (N + 63) / 64;
    int scatBlocks = (E + 4095) / 4096;
    gemm_and_scatter<<<gemmBlocks + scatBlocks, 256, 0, stream>>>(
        x, wt, att_src, att_dst, xq, pks, adst, N, ei, bucket_cnt, bucketbuf, E, gemmBlocks);

    bucket_csr<<<NB, 512, 0, stream>>>(bucketbuf, bucket_cnt, pks, adst,
                                       rowptr, ssrc, wsbuf, selfws, wssumbuf, N, E, NB);

    int gn = (N + 7) / 8;   // 8 half-waves (8 nodes) per 256-thread block
    node_fused<<<gn, 256, 0, stream>>>(ssrc, rowptr, wsbuf, selfws, wssumbuf, xq, out, N);

    bn_stats<<<1024, 256, 0, stream>>>(out, sums, sqs, N);
    finalize<<<((N * 64) + 255) / 256, 256, 0, stream>>>(out, bnw, bnb, sums, sqs, N);
}

// Round 23
// 119.200 us; speedup vs baseline: 1.3589x; 1.3589x over previous
//
#include <hip/hip_runtime.h>

#define IN_CH 128
#define HC 256      // HEADS*OUT_CH
#define OUT_CH 64
#define NEG 0.2f
#define BN_EPS 1e-5f
#define APITCH 136   // bf16 LDS pitch
#define CSR_CAP 4096 // per-bucket capacity (128 dst nodes/bucket, avg ~2.2K edges)

typedef __attribute__((ext_vector_type(8))) short short8v;
typedef __attribute__((ext_vector_type(4))) float f32x4v;

// ---------- helpers ----------
__device__ __forceinline__ float4 add4(float4 a, float4 b) {
    return make_float4(a.x + b.x, a.y + b.y, a.z + b.z, a.w + b.w);
}
__device__ __forceinline__ float4 mul4(float4 a, float4 b) {
    return make_float4(a.x * b.x, a.y * b.y, a.z * b.z, a.w * b.w);
}
__device__ __forceinline__ float4 exp4f(float4 a) {
    return make_float4(__expf(a.x), __expf(a.y), __expf(a.z), __expf(a.w));
}
__device__ __forceinline__ float4 leaky4(float4 v) {
    v.x = v.x > 0.f ? v.x : v.x * NEG;
    v.y = v.y > 0.f ? v.y : v.y * NEG;
    v.z = v.z > 0.f ? v.z : v.z * NEG;
    v.w = v.w > 0.f ? v.w : v.w * NEG;
    return v;
}
__device__ __forceinline__ unsigned short f2bf(float f) {
    unsigned u = __float_as_uint(f);
    unsigned r = u + 0x7fffu + ((u >> 16) & 1u);   // round-to-nearest-even
    return (unsigned short)(r >> 16);
}
// int8 dequant-accumulate: 4 biased bytes of u scaled by ws into acc
__device__ __forceinline__ void acc8(float4& a, float ws, unsigned u) {
    a.x += ws * (float)(u & 0xffu);
    a.y += ws * (float)((u >> 8) & 0xffu);
    a.z += ws * (float)((u >> 16) & 0xffu);
    a.w += ws * (float)(u >> 24);
}

// ---- K0: wt in MFMA-FRAGMENT order + zero bucket_cnt/sums/sqs (640 words) ----
__global__ __launch_bounds__(256) void prep_wt(const float* __restrict__ W,
                                               unsigned short* __restrict__ wt,
                                               unsigned* __restrict__ zeros, int nz) {
    int idx = blockIdx.x * 256 + threadIdx.x;
    if (idx < nz) zeros[idx] = 0u;
    if (idx >= 64 * 64) return;
    int frag = idx >> 6, l = idx & 63;
    int j = frag >> 2, ks = frag & 3;
    int c = l & 15, g = l >> 4;
    int ch = c * 16 + j;
    int k0 = ks * 32 + g * 8;
    unsigned up[4];
    #pragma unroll
    for (int q = 0; q < 4; ++q) {
        unsigned short lo = f2bf(W[(size_t)(k0 + 2 * q) * HC + ch]);
        unsigned short hi = f2bf(W[(size_t)(k0 + 2 * q + 1) * HC + ch]);
        up[q] = (unsigned)lo | ((unsigned)hi << 16);
    }
    *(uint4*)(wt + (size_t)idx * 8) = make_uint4(up[0], up[1], up[2], up[3]);
}

// ---- K1 (fat): blocks [0, gemmBlocks) = MFMA GEMM; rest = bucket_scatter ----
__global__ __launch_bounds__(256) void gemm_and_scatter(const float* __restrict__ x,
                                                        const unsigned short* __restrict__ wt,
                                                        const float* __restrict__ att_src,
                                                        const float* __restrict__ att_dst,
                                                        unsigned char* __restrict__ xq,
                                                        float* __restrict__ pks,
                                                        float* __restrict__ adst, int N,
                                                        const int* __restrict__ ei,
                                                        unsigned* __restrict__ bucket_cnt,
                                                        unsigned* __restrict__ bucketbuf,
                                                        int E, int gemmBlocks) {
    __shared__ unsigned short Al[64][APITCH];              // gemm path
    __shared__ unsigned lcnt[512], lbase[512], lcur[512];  // scatter path
    int t = threadIdx.x;

    if ((int)blockIdx.x >= gemmBlocks) {
        // ---------------- bucket_scatter ----------------
        lcnt[t] = 0u; lcnt[t + 256] = 0u;
        lcur[t] = 0u; lcur[t + 256] = 0u;
        __syncthreads();
        int c0 = ((int)blockIdx.x - gemmBlocks) * 4096;
        unsigned rec[16];
        int bk[16];
        #pragma unroll
        for (int i = 0; i < 16; ++i) {
            int e = c0 + t + i * 256;
            bk[i] = -1;
            if (e < E) {
                unsigned s = (unsigned)ei[e];
                unsigned d = (unsigned)ei[E + e];
                rec[i] = s | ((d & 127u) << 16);
                bk[i] = (int)(d >> 7);
                atomicAdd(&lcnt[bk[i]], 1u);
            }
        }
        __syncthreads();
        #pragma unroll
        for (int h = 0; h < 2; ++h) {
            int bi = t + h * 256;
            lbase[bi] = lcnt[bi] ? atomicAdd(&bucket_cnt[bi], lcnt[bi]) : 0u;
        }
        __syncthreads();
        #pragma unroll
        for (int i = 0; i < 16; ++i) {
            if (bk[i] >= 0) {
                unsigned p = lbase[bk[i]] + atomicAdd(&lcur[bk[i]], 1u);
                if (p < CSR_CAP) bucketbuf[(size_t)bk[i] * CSR_CAP + p] = rec[i];
            }
        }
        return;
    }

    // ---------------- gemm_mfma (LDS-staged A) ----------------
    int r0 = blockIdx.x * 64;
    #pragma unroll
    for (int i = 0; i < 8; ++i) {
        int f4 = t + i * 256;
        int m = f4 >> 5, kf = f4 & 31;
        float4 v = make_float4(0.f, 0.f, 0.f, 0.f);
        int r = r0 + m;
        if (r < N) v = *(const float4*)(x + (size_t)r * IN_CH + kf * 4);
        ushort4 pk;
        pk.x = f2bf(v.x); pk.y = f2bf(v.y); pk.z = f2bf(v.z); pk.w = f2bf(v.w);
        *(ushort4*)(&Al[m][kf * 4]) = pk;
    }
    __syncthreads();

    int w = t >> 6, l = t & 63;
    int c = l & 15, g = l >> 4;
    int arow = w * 16 + c;

    f32x4v acc[16];
    #pragma unroll
    for (int j = 0; j < 16; ++j) acc[j] = (f32x4v){0.f, 0.f, 0.f, 0.f};

    #pragma unroll
    for (int ks = 0; ks < 4; ++ks) {
        short8v a = *(const short8v*)(&Al[arow][ks * 32 + g * 8]);
        #pragma unroll
        for (int j = 0; j < 16; ++j) {
            short8v b = *(const short8v*)(wt + (size_t)((j * 4 + ks) * 64 + l) * 8);
            acc[j] = __builtin_amdgcn_mfma_f32_16x16x32_bf16(a, b, acc[j], 0, 0, 0);
        }
    }

    float as_c[16], ad_c[16];
    #pragma unroll
    for (int q = 0; q < 4; ++q) {
        *(float4*)(&as_c[q * 4]) = *(const float4*)(att_src + c * 16 + q * 4);
        *(float4*)(&ad_c[q * 4]) = *(const float4*)(att_dst + c * 16 + q * 4);
    }
    #pragma unroll
    for (int i = 0; i < 4; ++i) {
        int r = r0 + w * 16 + g * 4 + i;
        float ps = 0.f, pd = 0.f;
        float amax = 0.f;
        #pragma unroll
        for (int j = 0; j < 16; ++j) {
            float av = acc[j][i];
            ps += av * as_c[j];
            pd += av * ad_c[j];
            amax = fmaxf(amax, fabsf(av));
        }
        ps += __shfl_xor(ps, 1, 64); pd += __shfl_xor(pd, 1, 64);
        ps += __shfl_xor(ps, 2, 64); pd += __shfl_xor(pd, 2, 64);
        amax = fmaxf(amax, __shfl_xor(amax, 1, 64));
        amax = fmaxf(amax, __shfl_xor(amax, 2, 64));
        float inv = amax > 0.f ? 127.f / amax : 0.f;
        if (r < N) {
            int q4 = c & 3, h = c >> 2;
            if (q4 == 0) pks[(size_t)r * 8 + h] = ps;
            else if (q4 == 1) adst[(size_t)r * 4 + h] = pd;
            else if (q4 == 2) pks[(size_t)r * 8 + 4 + h] = amax * (1.f / 127.f);
            unsigned* orow = (unsigned*)(xq + (size_t)r * HC);
            #pragma unroll
            for (int q = 0; q < 4; ++q) {
                unsigned b0 = (unsigned)(int)fmaf(acc[q * 4 + 0][i], inv, 128.5f);
                unsigned b1 = (unsigned)(int)fmaf(acc[q * 4 + 1][i], inv, 128.5f);
                unsigned b2 = (unsigned)(int)fmaf(acc[q * 4 + 2][i], inv, 128.5f);
                unsigned b3 = (unsigned)(int)fmaf(acc[q * 4 + 3][i], inv, 128.5f);
                unsigned pk = b0 | (b1 << 8) | (b2 << 16) | (b3 << 24);
                orow[(((c & 3) * 4 + q) << 2) + h] = pk;
            }
        }
    }
}

// ---- CSR pass B: one 512-thread block per 128-dst bucket ----
__global__ __launch_bounds__(512) void bucket_csr(const unsigned* __restrict__ bucketbuf,
                                                  const unsigned* __restrict__ bucket_cnt,
                                                  unsigned* __restrict__ rowptr,
                                                  unsigned short* __restrict__ ssrc,
                                                  int N, int E, int NB) {
    __shared__ unsigned csum[512];
    __shared__ unsigned dcnt[128], dscan[128], curo[128];
    __shared__ unsigned short sstage[CSR_CAP];
    int b = blockIdx.x, t = threadIdx.x;
    csum[t] = (t < NB) ? bucket_cnt[t] : 0u;
    if (t < 128) dcnt[t] = 0u;
    __syncthreads();
    for (int o = 1; o < 512; o <<= 1) {
        unsigned v = (t >= o) ? csum[t - o] : 0u;
        __syncthreads();
        csum[t] += v;
        __syncthreads();
    }
    unsigned base = (b == 0) ? 0u : csum[b - 1];
    unsigned nloc = bucket_cnt[b];
    if (nloc > CSR_CAP) nloc = CSR_CAP;
    const unsigned* bb = bucketbuf + (size_t)b * CSR_CAP;
    for (unsigned i = t; i < nloc; i += 512) atomicAdd(&dcnt[bb[i] >> 16], 1u);
    __syncthreads();
    if (t < 128) dscan[t] = dcnt[t];
    __syncthreads();
    for (int o = 1; o < 128; o <<= 1) {
        unsigned v = 0u;
        if (t < 128 && t >= o) v = dscan[t - o];
        __syncthreads();
        if (t < 128) dscan[t] += v;
        __syncthreads();
    }
    if (t < 128) {
        unsigned loff = dscan[t] - dcnt[t];
        curo[t] = loff;
        int node = b * 128 + t;
        if (node < N) rowptr[node] = base + loff;
    }
    if (b == 0 && t == 0) rowptr[N] = (unsigned)E;
    __syncthreads();
    for (unsigned i = t; i < nloc; i += 512) {
        unsigned r = bb[i];
        unsigned p = atomicAdd(&curo[r >> 16], 1u);
        sstage[p] = (unsigned short)(r & 0xffffu);
    }
    __syncthreads();
    for (unsigned i = t; i < nloc; i += 512) ssrc[base + i] = sstage[i];
}

// ---- K_fused: HALF-WAVE per node. Two nodes per 64-lane wave, all cross-lane
// ops width-32. Fast path deg<32 (lane deg = self); slow path deg>=32. ----
__global__ __launch_bounds__(256) void node_fused(const unsigned short* __restrict__ ssrc,
                                                  const unsigned* __restrict__ rowptr,
                                                  const float* __restrict__ pks,
                                                  const float* __restrict__ adst,
                                                  const unsigned char* __restrict__ xq,
                                                  float* __restrict__ out, int N) {
    int wid = (blockIdx.x * 256 + threadIdx.x) >> 5;   // half-wave index = node
    if (wid >= N) return;
    int hlane = threadIdx.x & 31;
    int row0 = rowptr[wid];
    int deg = (int)rowptr[wid + 1] - row0;

    float4 ad = *(const float4*)(adst + (size_t)wid * 4);
    float4 saw = *(const float4*)(pks + (size_t)wid * 8);      // self asrc
    float4 scw = *(const float4*)(pks + (size_t)wid * 8 + 4);  // self scale

    bool isEdge = hlane < deg;
    bool active = hlane <= deg;        // deg<32: lane deg = self
    int s0 = wid;
    float4 as_s = saw, sc_s = scw;
    if (isEdge) {
        s0 = ssrc[row0 + hlane];
        as_s = *(const float4*)(pks + (size_t)s0 * 8);
        sc_s = *(const float4*)(pks + (size_t)s0 * 8 + 4);
    }
    float4 ex0 = make_float4(0.f, 0.f, 0.f, 0.f);
    if (deg < 32 ? active : true) ex0 = exp4f(leaky4(add4(as_s, ad)));
    float4 sum = ex0;
    if (deg >= 32) {
        for (int j = hlane + 32; j < deg; j += 32) {
            int s = ssrc[row0 + j];
            float4 lv = leaky4(add4(*(const float4*)(pks + (size_t)s * 8), ad));
            sum = add4(sum, exp4f(lv));
        }
        if (hlane == 31) sum = add4(sum, exp4f(leaky4(add4(saw, ad))));
    }
    #pragma unroll
    for (int m = 1; m < 32; m <<= 1) {
        sum.x += __shfl_xor(sum.x, m, 32);
        sum.y += __shfl_xor(sum.y, m, 32);
        sum.z += __shfl_xor(sum.z, m, 32);
        sum.w += __shfl_xor(sum.w, m, 32);
    }
    float4 inv4 = make_float4(0.25f / sum.x, 0.25f / sum.y, 0.25f / sum.z, 0.25f / sum.w);
    float4 wsv = mul4(mul4(ex0, sc_s), inv4);   // per-lane weights (0 on idle lanes)

    int grp = hlane >> 4, sub = hlane & 15;
    float4 acc = make_float4(0.f, 0.f, 0.f, 0.f);
    float wssum = 0.f;

    if (deg < 32) {
        int nIter = (deg + 2) >> 1;             // ceil((deg+1)/2)
        #pragma unroll 4
        for (int it = 0; it < nIter; ++it) {
            int e = it * 2 + grp;               // e <= 32; clamp via wsv=0 lanes
            int ec = e < 32 ? e : 0;
            int s = __shfl(s0, ec, 32);
            float w0 = __shfl(wsv.x, ec, 32), w1 = __shfl(wsv.y, ec, 32);
            float w2 = __shfl(wsv.z, ec, 32), w3 = __shfl(wsv.w, ec, 32);
            if (e >= 32) { w0 = w1 = w2 = w3 = 0.f; s = wid; }
            uint4 u = *(const uint4*)(xq + (size_t)s * HC + sub * 16);
            acc8(acc, w0, u.x); acc8(acc, w1, u.y);
            acc8(acc, w2, u.z); acc8(acc, w3, u.w);
            wssum += w0 + w1 + w2 + w3;
        }
    } else {
        float4 selfws = mul4(mul4(exp4f(leaky4(add4(saw, ad))), scw), inv4);
        for (int jb = 0; jb <= deg; jb += 2) {
            int e = jb + grp;
            int ec = e < 32 ? e : 0;
            int s_sh = __shfl(s0, ec, 32);
            float w0 = __shfl(wsv.x, ec, 32), w1 = __shfl(wsv.y, ec, 32);
            float w2 = __shfl(wsv.z, ec, 32), w3 = __shfl(wsv.w, ec, 32);
            int s;
            float4 wv4;
            if (e < deg) {
                if (e < 32) {
                    s = s_sh;
                    wv4 = make_float4(w0, w1, w2, w3);
                } else {
                    s = ssrc[row0 + e];
                    float4 glv = leaky4(add4(*(const float4*)(pks + (size_t)s * 8), ad));
                    float4 gsc = *(const float4*)(pks + (size_t)s * 8 + 4);
                    wv4 = mul4(mul4(exp4f(glv), gsc), inv4);
                }
            } else if (e == deg) {
                s = wid; wv4 = selfws;
            } else {
                s = wid; wv4 = make_float4(0.f, 0.f, 0.f, 0.f);
            }
            uint4 u = *(const uint4*)(xq + (size_t)s * HC + sub * 16);
            acc8(acc, wv4.x, u.x); acc8(acc, wv4.y, u.y);
            acc8(acc, wv4.z, u.z); acc8(acc, wv4.w, u.w);
            wssum += wv4.x + wv4.y + wv4.z + wv4.w;
        }
    }

    // combine the 2 edge-groups (xor 16, width 32)
    acc.x += __shfl_xor(acc.x, 16, 32);
    acc.y += __shfl_xor(acc.y, 16, 32);
    acc.z += __shfl_xor(acc.z, 16, 32);
    acc.w += __shfl_xor(acc.w, 16, 32);
    wssum += __shfl_xor(wssum, 16, 32);
    float off = 128.f * wssum;
    if (hlane < 16) {
        float4 o4 = make_float4(acc.x - off, acc.y - off, acc.z - off, acc.w - off);
        *(float4*)(out + (size_t)wid * OUT_CH + sub * 4) = o4;
    }
}

// ---- K5: BN batch stats (bias cancels through BN -> omitted) ----
__global__ __launch_bounds__(256) void bn_stats(const float* __restrict__ out,
                                                float* __restrict__ sums,
                                                float* __restrict__ sqs, int N) {
    int c = threadIdx.x & 63, rl = threadIdx.x >> 6;
    float s = 0.f, q = 0.f;
    for (int r = blockIdx.x * 4 + rl; r < N; r += gridDim.x * 4) {
        float v = out[(size_t)r * 64 + c];
        s += v; q += v * v;
    }
    __shared__ float sb[256], qb[256];
    sb[threadIdx.x] = s; qb[threadIdx.x] = q;
    __syncthreads();
    if (rl == 0) {
        s = sb[c] + sb[64 + c] + sb[128 + c] + sb[192 + c];
        q = qb[c] + qb[64 + c] + qb[128 + c] + qb[192 + c];
        atomicAdd(sums + c, s);
        atomicAdd(sqs + c, q);
    }
}

// ---- K6: batchnorm + ELU, in place ----
__global__ __launch_bounds__(256) void finalize(float* __restrict__ out,
                                                const float* __restrict__ bnw,
                                                const float* __restrict__ bnb,
                                                const float* __restrict__ sums,
                                                const float* __restrict__ sqs, int N) {
    int idx = blockIdx.x * 256 + threadIdx.x;
    if (idx >= N * 64) return;
    int c = idx & 63;
    float invN = 1.0f / (float)N;
    float mu = sums[c] * invN;
    float var = sqs[c] * invN - mu * mu;
    float v = out[idx];
    float y = (v - mu) * rsqrtf(var + BN_EPS) * bnw[c] + bnb[c];
    out[idx] = y > 0.f ? y : expm1f(y);
}

extern "C" void kernel_launch(void* const* d_in, const int* in_sizes, int n_in,
                              void* d_out, int out_size, void* d_ws, size_t ws_size,
                              hipStream_t stream) {
    const float* x       = (const float*)d_in[0];
    const int*   ei      = (const int*)d_in[1];
    const float* W       = (const float*)d_in[2];
    const float* att_src = (const float*)d_in[3];
    const float* att_dst = (const float*)d_in[4];
    const float* bnw     = (const float*)d_in[6];
    const float* bnb     = (const float*)d_in[7];
    int N = in_sizes[0] / IN_CH;   // NOTE: src indices packed in uint16 (N < 65536)
    int E = in_sizes[1] / 2;
    float* out = (float*)d_out;
    int NB = (N + 127) / 128;      // 128 dsts per bucket

    // workspace layout (bucket_cnt, sums, sqs contiguous -> zeroed in prep_wt)
    unsigned char*  xq        = (unsigned char*)d_ws;                    // N*256 int8
    unsigned short* wt        = (unsigned short*)(xq + (size_t)N * HC);  // 64*64*8 bf16
    float*          pks       = (float*)(wt + 64 * 64 * 8);              // N*8 {asrc,scale}
    float*          adst      = pks + (size_t)N * 8;                     // N*4
    unsigned*       bucket_cnt= (unsigned*)(adst + (size_t)N * 4);       // 512
    float*          sums      = (float*)(bucket_cnt + 512);              // 64
    float*          sqs       = sums + 64;                               // 64
    unsigned*       rowptr    = (unsigned*)(sqs + 64);                   // N+1
    unsigned*       bucketbuf = rowptr + N + 1;                          // NB*CSR_CAP
    unsigned short* ssrc      = (unsigned short*)(bucketbuf + (size_t)NB * CSR_CAP); // E

    prep_wt<<<16, 256, 0, stream>>>(W, wt, bucket_cnt, 640);

    int gemmBlocks = (N + 63) / 64;
    int scatBlocks = (E + 4095) / 4096;
    gemm_and_scatter<<<gemmBlocks + scatBlocks, 256, 0, stream>>>(
        x, wt, att_src, att_dst, xq, pks, adst, N, ei, bucket_cnt, bucketbuf, E, gemmBlocks);

    bucket_csr<<<NB, 512, 0, stream>>>(bucketbuf, bucket_cnt, rowptr, ssrc, N, E, NB);

    int gn = (N + 7) / 8;   // 8 half-waves (8 nodes) per 256-thread block
    node_fused<<<gn, 256, 0, stream>>>(ssrc, rowptr, pks, adst, xq, out, N);

    bn_stats<<<1024, 256, 0, stream>>>(out, sums, sqs, N);
    finalize<<<((N * 64) + 255) / 256, 256, 0, stream>>>(out, bnw, bnb, sums, sqs, N);
}